// Round 1
// baseline (153.250 us; speedup 1.0000x reference)
//
#include <hip/hip_runtime.h>
#include <math.h>

// ConvCaps EM-routing, MI355X.
//
// Shapes: x(64,32,14,14,4,4) a(64,32,14,14) w(1,32,6,6,4,4,32) b_u(32) b_a(32)
// Outputs: mu flat (2304*512) then a_out flat (2304*32).
//
// All reference reshapes are raw flat reinterpretations; we work in flat index
// space. Conv weight is constant 1/9 => conv output is independent of the
// output channel: S[n2,oy,ox] (n2<1024) for x-view, A[b,oy,ox] (b<64) for a.

#define EPSF 1e-8f
#define LOG2PI_F 1.8378770664093453f

__global__ void conv_stat_kernel(const float* __restrict__ x,
                                 const float* __restrict__ a,
                                 float* __restrict__ S,
                                 float* __restrict__ A) {
    int t = blockIdx.x * blockDim.x + threadIdx.x;
    if (t >= 36864 + 2304) return;
    bool isA = (t >= 36864);
    int tt = isA ? (t - 36864) : t;
    int n2 = tt / 36;
    int sp = tt % 36;
    int oy = sp / 6, ox = sp % 6;
    // both x-view (1024,32,14,14) and a (64,32,14,14) have n-stride 6272
    const float* src = isA ? a : x;
    const float* base = src + (size_t)n2 * 6272 + (2 * oy) * 14 + (2 * ox);
    float s = 0.f;
    for (int c = 0; c < 32; ++c) {
        const float* p = base + c * 196;
#pragma unroll
        for (int ky = 0; ky < 3; ++ky)
            s += p[ky * 14] + p[ky * 14 + 1] + p[ky * 14 + 2];
    }
    float val = s * (1.0f / 9.0f);
    if (isA) A[tt] = val; else S[tt] = val;
}

// One workgroup per routing group n (2304 groups).
// LDS-resident v[c][o][k] (rows padded to 17 floats: 17 coprime 32 => the
// e-step's per-o stride-16 access pattern is bank-conflict-free).
__global__ __launch_bounds__(256) void em_kernel(
        const float* __restrict__ w,
        const float* __restrict__ bu,
        const float* __restrict__ ba,
        const float* __restrict__ S,
        const float* __restrict__ A,
        float* __restrict__ out) {
    __shared__ float v[17408];     // [ (c*32+o)*17 + k ]
    __shared__ float rr[1024];     // r[c*32+o] (holds r, then r*a+EPS, then softmax r)
    __shared__ float mu_s[512];    // [o*16+k]
    __shared__ float ls_s[512];    // 0.5*log(sig)
    __shared__ float i2s_s[512];   // 0.5/sig
    __shared__ float red[256];
    __shared__ float avs[32];
    __shared__ float rsum_s[32];
    __shared__ float rinv_s[32];
    __shared__ float aout_s[32];

    const int n = blockIdx.x;
    const int t = threadIdx.x;

    // av[n,c] = A-gather via flat reinterpretation of a_conv (64,32,6,6)->(2304,32)
    if (t < 32) {
        int flat = n * 32 + t;
        int b = flat / 1152;
        int rem = flat - b * 1152;
        avs[t] = A[b * 36 + rem % 36];
    }
    for (int i = t; i < 1024; i += 256) rr[i] = 0.03125f;  // 1/co

    // ---- build v[c][o][k] ----
    // vv flat = n*16384 + e reinterprets v_final (64,32,6,6,4,4,32):
    //   b=flat/589824, cc, y, x, local=p*128+q*32+o'; (om,i,j) = local as (32,4,4)
    // v_mat[..om,i,j] = sum_kk xv[..om,i,kk] * wv[..om,kk,j]
    //   xv: l1=om*16+i*4+kk -> xc_view flat xbase + (l1>>5) -> S gather
    //   wv: l2=om*16+kk*4+j -> w[wbase + l2]
    const int bq = n / 36;
    const int r1base = (n - bq * 36) * 16384;
    const int xb0 = bq * 18432;
    for (int e = t; e < 16384; e += 256) {
        int r1 = r1base + e;
        int cc = r1 / 18432;
        int r2 = r1 - cc * 18432;
        int y = r2 / 3072;
        int r3 = r2 - y * 3072;
        int xq = r3 >> 9;
        int local = r3 & 511;
        int om = local >> 4;
        int i4 = (local >> 2) & 3;
        int j = local & 3;
        int wbase = r1 - local;                       // cc*18432 + y*3072 + xq*512
        int xbase = xb0 + cc * 576 + y * 96 + xq * 16;
        float acc = 0.f;
#pragma unroll
        for (int kk = 0; kk < 4; ++kk) {
            int l1 = om * 16 + i4 * 4 + kk;
            int l2 = om * 16 + kk * 4 + j;
            int fx = xbase + (l1 >> 5);
            int n2x = fx / 1152;
            int remx = fx - n2x * 1152;
            acc += S[n2x * 36 + remx % 36] * w[wbase + l2];
        }
        int row = e >> 4;                             // c*32+o
        v[row * 17 + (e & 15)] = acc;
    }
    __syncthreads();

    const float lambdas[3] = {5.0e-4f, 9.75e-4f, 1.42625e-3f};

    for (int it = 0; it < 3; ++it) {
        const float lambd = lambdas[it];
        // rp = r*a + EPS (in place)
        for (int i = t; i < 1024; i += 256)
            rr[i] = rr[i] * avs[i >> 5] + EPSF;
        __syncthreads();
        // rsum[o] = sum_c rp[c,o]
        {
            int o = t >> 3, g = t & 7;
            float p = 0.f;
#pragma unroll
            for (int c = g; c < 32; c += 8) p += rr[c * 32 + o];
            red[t] = p;
        }
        __syncthreads();
        if (t < 32) {
            float s = 0.f;
#pragma unroll
            for (int g = 0; g < 8; ++g) s += red[t * 8 + g];
            rsum_s[t] = s;
            rinv_s[t] = 1.0f / s;
        }
        __syncthreads();
        // mu[o,k]
        for (int e = t; e < 512; e += 256) {
            int o = e >> 4;
            int vb = o * 17 + (e & 15);
            float s = 0.f;
#pragma unroll 8
            for (int c = 0; c < 32; ++c)
                s += rr[c * 32 + o] * v[c * 544 + vb];
            mu_s[e] = s * rinv_s[o];
        }
        __syncthreads();
        // sig[o,k] -> store 0.5*log(sig) and 0.5/sig
        for (int e = t; e < 512; e += 256) {
            int o = e >> 4;
            int vb = o * 17 + (e & 15);
            float m = mu_s[e];
            float s = 0.f;
#pragma unroll 8
            for (int c = 0; c < 32; ++c) {
                float d = v[c * 544 + vb] - m;
                s += rr[c * 32 + o] * d * d;
            }
            float sg = s * rinv_s[o] + EPSF;
            ls_s[e] = 0.5f * logf(sg);
            i2s_s[e] = 0.5f / sg;
        }
        __syncthreads();
        // cost & a_out
        if (t < 32) {
            float cs = 0.f;
#pragma unroll
            for (int k = 0; k < 16; ++k) cs += ls_s[t * 16 + k];
            cs = (cs + 16.0f * bu[t]) * rsum_s[t];
            float z = lambd * (ba[t] - cs);
            aout_s[t] = 1.0f / (1.0f + expf(-z));
        }
        __syncthreads();
        if (it < 2) {
            // e-step: ap[c,o] then softmax over o
            for (int pair = t; pair < 1024; pair += 256) {
                int c = pair >> 5, o = pair & 31;
                int vb = c * 544 + o * 17;
                int mb = o * 16;
                float s = 0.f;
#pragma unroll
                for (int k = 0; k < 16; ++k) {
                    float d = v[vb + k] - mu_s[mb + k];
                    s -= d * d * i2s_s[mb + k] + ls_s[mb + k];
                }
                rr[pair] = s - 8.0f * LOG2PI_F + logf(aout_s[o]);
            }
            __syncthreads();
            if (t < 32) {
                const int c = t;
                float m = -3.0e38f;
#pragma unroll
                for (int o = 0; o < 32; ++o) m = fmaxf(m, rr[c * 32 + o]);
                float ssum = 0.f;
#pragma unroll
                for (int o = 0; o < 32; ++o) {
                    float e_ = expf(rr[c * 32 + o] - m);
                    rr[c * 32 + o] = e_;
                    ssum += e_;
                }
                float inv = 1.0f / ssum;
#pragma unroll
                for (int o = 0; o < 32; ++o) rr[c * 32 + o] *= inv;
            }
            __syncthreads();
        }
    }

    // outputs: mu flat then a_out flat (reference reshapes are contiguity-preserving)
    float* out_mu = out;
    float* out_a = out + 1179648;
    for (int e = t; e < 512; e += 256)
        out_mu[n * 512 + e] = mu_s[e];
    if (t < 32) out_a[n * 32 + t] = aout_s[t];
}

extern "C" void kernel_launch(void* const* d_in, const int* in_sizes, int n_in,
                              void* d_out, int out_size, void* d_ws, size_t ws_size,
                              hipStream_t stream) {
    const float* x = (const float*)d_in[0];
    const float* a = (const float*)d_in[1];
    const float* w = (const float*)d_in[2];
    const float* bu = (const float*)d_in[3];
    const float* ba = (const float*)d_in[4];
    float* out = (float*)d_out;
    float* S = (float*)d_ws;        // 36864 floats
    float* A = S + 36864;           // 2304 floats

    conv_stat_kernel<<<(36864 + 2304 + 255) / 256, 256, 0, stream>>>(x, a, S, A);
    em_kernel<<<2304, 256, 0, stream>>>(w, bu, ba, S, A, out);
}

// Round 2
// 39.122 us; speedup vs baseline: 3.9172x; 3.9172x over previous
//
#include <hip/hip_runtime.h>
#include <math.h>

// ConvCaps EM-routing, MI355X — collapsed-v formulation.
//
// Key algebra: vv[n,ci,co,k] = Sv(n,ci,co>>1) * Wsum(sp=n%36,ci,co,k&3)
// (the 4x4 matmul's row index i=k>>2 drops out because the xv gather index
// l1>>5 == co>>1 for all (i,kk)).  So v has only 4 distinct values per
// (ci,co) and the whole EM loop runs on a 32x32x4 LDS table.

#define EPSF 1e-8f
#define LOG2PI_F 1.8378770664093453f

// ---- stage 1: channel sums of x-view (1024,32,14,14) and a (64,32,14,14) ----
__global__ void sum_kernel(const float* __restrict__ x, const float* __restrict__ a,
                           float* __restrict__ Xsum, float* __restrict__ Asum) {
    int t = blockIdx.x * blockDim.x + threadIdx.x;
    const int NX = 1024 * 196;
    if (t < NX) {
        int n2 = t / 196, hw = t - n2 * 196;
        const float* p = x + (size_t)n2 * 6272 + hw;
        float s = 0.f;
#pragma unroll
        for (int c = 0; c < 32; ++c) s += p[c * 196];
        Xsum[t] = s;
    } else if (t < NX + 64 * 196) {
        int tt = t - NX;
        int b = tt / 196, hw = tt - b * 196;
        const float* p = a + (size_t)b * 6272 + hw;
        float s = 0.f;
#pragma unroll
        for (int c = 0; c < 32; ++c) s += p[c * 196];
        Asum[tt] = s;
    }
}

// ---- stage 2: 3x3 stride-2 box filter (S, A) + Wsum[36][32][32][4] ----
__global__ void stat_kernel(const float* __restrict__ Xsum, const float* __restrict__ Asum,
                            const float* __restrict__ w,
                            float* __restrict__ S, float* __restrict__ A,
                            float* __restrict__ Wsum) {
    int t = blockIdx.x * blockDim.x + threadIdx.x;
    if (t < 36864) {
        int n2 = t / 36, sp = t - n2 * 36;
        int oy = sp / 6, ox = sp - oy * 6;
        const float* p = Xsum + n2 * 196 + oy * 28 + ox * 2;
        float s = 0.f;
#pragma unroll
        for (int ky = 0; ky < 3; ++ky) s += p[ky * 14] + p[ky * 14 + 1] + p[ky * 14 + 2];
        S[t] = s * (1.0f / 9.0f);
    } else if (t < 39168) {
        int tt = t - 36864;
        int b = tt / 36, sp = tt - b * 36;
        int oy = sp / 6, ox = sp - oy * 6;
        const float* p = Asum + b * 196 + oy * 28 + ox * 2;
        float s = 0.f;
#pragma unroll
        for (int ky = 0; ky < 3; ++ky) s += p[ky * 14] + p[ky * 14 + 1] + p[ky * 14 + 2];
        A[tt] = s * (1.0f / 9.0f);
    } else if (t < 39168 + 147456) {
        int wi = t - 39168;
        int sp = wi >> 12;              // /4096
        int r = wi & 4095;
        int ci = r >> 7, co = (r >> 2) & 31, j = r & 3;
        int B = sp * 32 + ci;
        int cc = B / 36;
        int rem = B - cc * 36;
        int wbase = cc * 18432 + (rem / 6) * 3072 + (rem % 6) * 512 + co * 16 + j;
        Wsum[wi] = w[wbase] + w[wbase + 4] + w[wbase + 8] + w[wbase + 12];
    }
}

// ---- stage 3: one workgroup per routing group n ----
__global__ __launch_bounds__(256) void em_kernel(
        const float* __restrict__ bu,
        const float* __restrict__ ba,
        const float* __restrict__ S,
        const float* __restrict__ A,
        const float* __restrict__ Wsum,
        float* __restrict__ out) {
    __shared__ float V4[5120];      // [c*160 + o*5 + j]  (stride 5 coprime 32)
    __shared__ float Sv[512];       // [c*16 + hc]
    __shared__ float rr[1024];      // r[c*32+o]
    __shared__ float mu4[160], ls4[160], i2s4[160];
    __shared__ float red[256];
    __shared__ float avs[32], rsum_s[32], rinv_s[32], aout_s[32];

    const int n = blockIdx.x;
    const int t = threadIdx.x;
    const int bq = n / 36;
    const int sp = n - bq * 36;

    // av[n,c]: flat reinterpretation of a_conv (64,32,6,6)->(2304,32)
    if (t < 32) {
        int flat = n * 32 + t;
        int b = flat / 1152;
        int rem = flat - b * 1152;
        avs[t] = A[b * 36 + rem % 36];
    }
    for (int i = t; i < 1024; i += 256) rr[i] = 0.03125f;

    // Sv[ci][hc] gather (hc = co>>1)
    for (int e = t; e < 512; e += 256) {
        int ci = e >> 4, hc = e & 15;
        int B = sp * 32 + ci;
        int cc = B / 36;
        int rem = B - cc * 36;
        int off = cc * 576 + (rem / 6) * 96 + (rem % 6) * 16 + hc;
        int hi = off / 1152;
        int lo = off - hi * 1152;
        Sv[e] = S[(bq * 16 + hi) * 36 + lo % 36];
    }
    __syncthreads();

    // V4[c][o][j] = Sv[c][o>>1] * Wsum[sp][c][o][j]
    const float* Wn = Wsum + sp * 4096;
    for (int e = t; e < 4096; e += 256) {
        int c = e >> 7, o = (e >> 2) & 31, j = e & 3;
        V4[c * 160 + o * 5 + j] = Sv[c * 16 + (o >> 1)] * Wn[e];
    }
    __syncthreads();

    const float lambdas[3] = {5.0e-4f, 9.75e-4f, 1.42625e-3f};

    for (int it = 0; it < 3; ++it) {
        // rp = r*a + EPS
        for (int i = t; i < 1024; i += 256)
            rr[i] = rr[i] * avs[i >> 5] + EPSF;
        __syncthreads();
        // rsum[o]
        {
            int o = t >> 3, g = t & 7;
            float p = 0.f;
#pragma unroll
            for (int c = g; c < 32; c += 8) p += rr[c * 32 + o];
            red[t] = p;
        }
        __syncthreads();
        if (t < 32) {
            float s = 0.f;
#pragma unroll
            for (int g = 0; g < 8; ++g) s += red[t * 8 + g];
            rsum_s[t] = s;
            rinv_s[t] = 1.0f / s;
        }
        __syncthreads();
        // mu4[o,j]
        if (t < 128) {
            int o = t >> 2, j = t & 3;
            float s = 0.f;
#pragma unroll 8
            for (int c = 0; c < 32; ++c)
                s += rr[c * 32 + o] * V4[c * 160 + o * 5 + j];
            mu4[o * 5 + j] = s * rinv_s[o];
        }
        __syncthreads();
        // sig4[o,j] -> 0.5*log(sig), 0.5/sig
        if (t < 128) {
            int o = t >> 2, j = t & 3;
            float m = mu4[o * 5 + j];
            float s = 0.f;
#pragma unroll 8
            for (int c = 0; c < 32; ++c) {
                float d = V4[c * 160 + o * 5 + j] - m;
                s += rr[c * 32 + o] * d * d;
            }
            float sg = s * rinv_s[o] + EPSF;
            ls4[o * 5 + j] = 0.5f * __logf(sg);
            i2s4[o * 5 + j] = 0.5f / sg;
        }
        __syncthreads();
        // cost & a_out  (sum over 16 k = 4 * sum over j)
        if (t < 32) {
            float cs = ls4[t * 5] + ls4[t * 5 + 1] + ls4[t * 5 + 2] + ls4[t * 5 + 3];
            float cost = (16.0f * bu[t] + 4.0f * cs) * rsum_s[t];
            float z = lambdas[it] * (ba[t] - cost);
            aout_s[t] = 1.0f / (1.0f + __expf(-z));
        }
        __syncthreads();
        if (it < 2) {
            // e-step logits
            for (int pair = t; pair < 1024; pair += 256) {
                int c = pair >> 5, o = pair & 31;
                float s = 0.f;
#pragma unroll
                for (int j = 0; j < 4; ++j) {
                    float d = V4[c * 160 + o * 5 + j] - mu4[o * 5 + j];
                    s -= d * d * i2s4[o * 5 + j] + ls4[o * 5 + j];
                }
                rr[pair] = 4.0f * s - 8.0f * LOG2PI_F + __logf(aout_s[o]);
            }
            __syncthreads();
            // softmax over o, 8 lanes per c (register shuffle reduce)
            {
                int c = t >> 3, og = t & 7;
                int base = c * 32 + og * 4;
                float v0 = rr[base], v1 = rr[base + 1], v2 = rr[base + 2], v3 = rr[base + 3];
                float m = fmaxf(fmaxf(v0, v1), fmaxf(v2, v3));
                m = fmaxf(m, __shfl_xor(m, 1));
                m = fmaxf(m, __shfl_xor(m, 2));
                m = fmaxf(m, __shfl_xor(m, 4));
                v0 = __expf(v0 - m); v1 = __expf(v1 - m);
                v2 = __expf(v2 - m); v3 = __expf(v3 - m);
                float ssum = v0 + v1 + v2 + v3;
                ssum += __shfl_xor(ssum, 1);
                ssum += __shfl_xor(ssum, 2);
                ssum += __shfl_xor(ssum, 4);
                float inv = 1.0f / ssum;
                rr[base] = v0 * inv; rr[base + 1] = v1 * inv;
                rr[base + 2] = v2 * inv; rr[base + 3] = v3 * inv;
            }
            __syncthreads();
        }
    }

    // outputs: mu expanded back to 16 k (k>>2 drops out), then a_out
    for (int e = t; e < 512; e += 256) {
        int o = e >> 4, k = e & 15;
        out[n * 512 + e] = mu4[o * 5 + (k & 3)];
    }
    if (t < 32) out[1179648 + n * 32 + t] = aout_s[t];
}

extern "C" void kernel_launch(void* const* d_in, const int* in_sizes, int n_in,
                              void* d_out, int out_size, void* d_ws, size_t ws_size,
                              hipStream_t stream) {
    const float* x = (const float*)d_in[0];
    const float* a = (const float*)d_in[1];
    const float* w = (const float*)d_in[2];
    const float* bu = (const float*)d_in[3];
    const float* ba = (const float*)d_in[4];
    float* out = (float*)d_out;

    float* Xsum = (float*)d_ws;          // 200704
    float* Asum = Xsum + 200704;         // 12544
    float* S    = Asum + 12544;          // 36864
    float* A    = S + 36864;             // 2304
    float* Wsum = A + 2304;              // 147456   (total 399872 floats = 1.6 MB)

    sum_kernel<<<(200704 + 12544 + 255) / 256, 256, 0, stream>>>(x, a, Xsum, Asum);
    stat_kernel<<<(39168 + 147456 + 255) / 256, 256, 0, stream>>>(Xsum, Asum, w, S, A, Wsum);
    em_kernel<<<2304, 256, 0, stream>>>(bu, ba, S, A, Wsum, out);
}

// Round 3
// 35.227 us; speedup vs baseline: 4.3504x; 1.1106x over previous
//
#include <hip/hip_runtime.h>
#include <math.h>

// ConvCaps EM-routing, MI355X — wave-per-group, register-resident EM.
//
// Algebra recap: vv[n,ci,co,k] = Sv(n,ci,co>>1) * Wsum(sp=n%36,ci,co,k&3),
// so the EM loop runs on a 32x32x4 table. One 64-lane wave per group:
// lane=(h,o), h=c-half, o=co. All reductions are 16 in-register adds +
// one shfl_xor(32); softmax over o is a 5-level shfl_xor within each half.

#define EPSF 1e-8f
#define LOG2PI_F 1.8378770664093453f

// ---- pre: box-filtered channel sums (S,A) + Wsum[36][32][32][4] ----
__global__ __launch_bounds__(256) void pre_kernel(
        const float* __restrict__ x, const float* __restrict__ a,
        const float* __restrict__ w,
        float* __restrict__ S, float* __restrict__ A, float* __restrict__ Wsum) {
    int bid = blockIdx.x;
    if (bid < 272) {
        // 4 planes per block, one wave each: channel-sum a 14x14 plane, then 3x3/2 box.
        __shared__ float plane[4][200];
        int wv = threadIdx.x >> 6, lane = threadIdx.x & 63;
        int p = bid * 4 + wv;                       // 0..1087 (1024 x-planes + 64 a-planes)
        const float* src = (p < 1024) ? (x + (size_t)p * 6272)
                                      : (a + (size_t)(p - 1024) * 6272);
        if (lane < 49) {
            float4 s = {0.f, 0.f, 0.f, 0.f};
            for (int c = 0; c < 32; ++c) {
                float4 v = *(const float4*)(src + c * 196 + lane * 4);
                s.x += v.x; s.y += v.y; s.z += v.z; s.w += v.w;
            }
            *(float4*)(&plane[wv][lane * 4]) = s;
        }
        __syncthreads();
        if (lane < 36) {
            int oy = lane / 6, ox = lane - oy * 6;
            const float* q = &plane[wv][oy * 28 + ox * 2];
            float s = q[0] + q[1] + q[2] + q[14] + q[15] + q[16] + q[28] + q[29] + q[30];
            s *= (1.0f / 9.0f);
            if (p < 1024) S[p * 36 + lane] = s;
            else          A[(p - 1024) * 36 + lane] = s;
        }
    } else {
        int wi = (bid - 272) * 256 + threadIdx.x;   // 147456 Wsum entries
        int sp = wi >> 12;
        int r = wi & 4095;
        int ci = r >> 7, co = (r >> 2) & 31, j = r & 3;
        int B = sp * 32 + ci;
        int cc = B / 36;
        int rem = B - cc * 36;
        int wbase = cc * 18432 + (rem / 6) * 3072 + (rem % 6) * 512 + co * 16 + j;
        Wsum[wi] = w[wbase] + w[wbase + 4] + w[wbase + 8] + w[wbase + 12];
    }
}

// ---- EM: one wave per routing group, 4 groups per 256-thread block ----
__global__ __launch_bounds__(256) void em_kernel(
        const float* __restrict__ bu, const float* __restrict__ ba,
        const float* __restrict__ S, const float* __restrict__ A,
        const float* __restrict__ Wsum, float* __restrict__ out) {
    __shared__ float Sv[4][512];
    __shared__ float avs[4][32];

    const int t = threadIdx.x;
    const int g = t >> 6;
    const int lane = t & 63;
    const int h = lane >> 5;       // c-half
    const int o = lane & 31;       // output capsule
    const int n = blockIdx.x * 4 + g;
    const int bq = n / 36;
    const int sp = n - bq * 36;

    // stage av[n][c] (flat reinterpretation of a_conv (64,32,6,6)->(2304,32))
    if (lane < 32) {
        int flat = n * 32 + lane;
        int b = flat / 1152;
        int rem = flat - b * 1152;
        avs[g][lane] = A[b * 36 + rem % 36];
    }
    // stage Sv[ci][hc] gather
    for (int e = lane; e < 512; e += 64) {
        int ci = e >> 4, hc = e & 15;
        int B = sp * 32 + ci;
        int cc = B / 36;
        int rem = B - cc * 36;
        int off = cc * 576 + (rem / 6) * 96 + (rem % 6) * 16 + hc;
        int hi = off / 1152;
        int lo = off - hi * 1152;
        Sv[g][e] = S[(bq * 16 + hi) * 36 + lo % 36];
    }
    __syncthreads();

    // register-resident V4 slice: Vreg[cl][j] for c = h*16+cl
    const int hc = o >> 1;
    float Vreg[16][4], avr[16], r[16];
    const float* Wn = Wsum + sp * 4096;
#pragma unroll
    for (int cl = 0; cl < 16; ++cl) {
        int c = h * 16 + cl;
        float sv = Sv[g][c * 16 + hc];
        float4 w4 = *(const float4*)(Wn + c * 128 + o * 4);
        Vreg[cl][0] = sv * w4.x; Vreg[cl][1] = sv * w4.y;
        Vreg[cl][2] = sv * w4.z; Vreg[cl][3] = sv * w4.w;
        avr[cl] = avs[g][c];
        r[cl] = 0.03125f;
    }
    const float bu_o = bu[o];
    const float ba_o = ba[o];
    float mu[4], ls[4], i2s[4], aout = 0.f;
    const float lambdas[3] = {5.0e-4f, 9.75e-4f, 1.42625e-3f};

    for (int it = 0; it < 3; ++it) {
        // rp = r*a + EPS ; rsum over all 32 c (own 16 + partner half)
        float rp[16];
        float rs = 0.f;
#pragma unroll
        for (int cl = 0; cl < 16; ++cl) { rp[cl] = r[cl] * avr[cl] + EPSF; rs += rp[cl]; }
        rs += __shfl_xor(rs, 32);
        float rinv = 1.0f / rs;
        // mu[j]
#pragma unroll
        for (int j = 0; j < 4; ++j) {
            float s = 0.f;
#pragma unroll
            for (int cl = 0; cl < 16; ++cl) s += rp[cl] * Vreg[cl][j];
            s += __shfl_xor(s, 32);
            mu[j] = s * rinv;
        }
        // sig[j] -> 0.5*log, 0.5/sig
#pragma unroll
        for (int j = 0; j < 4; ++j) {
            float s = 0.f;
#pragma unroll
            for (int cl = 0; cl < 16; ++cl) {
                float d = Vreg[cl][j] - mu[j];
                s += rp[cl] * d * d;
            }
            s += __shfl_xor(s, 32);
            float sg = s * rinv + EPSF;
            ls[j] = 0.5f * __logf(sg);
            i2s[j] = 0.5f / sg;
        }
        float cost = (16.0f * bu_o + 4.0f * (ls[0] + ls[1] + ls[2] + ls[3])) * rs;
        float z = lambdas[it] * (ba_o - cost);
        aout = 1.0f / (1.0f + __expf(-z));

        if (it < 2) {
            float la = __logf(aout);
            float lg[16];
#pragma unroll
            for (int cl = 0; cl < 16; ++cl) {
                float s = 0.f;
#pragma unroll
                for (int j = 0; j < 4; ++j) {
                    float d = Vreg[cl][j] - mu[j];
                    s += d * d * i2s[j] + ls[j];
                }
                lg[cl] = -4.0f * s - 8.0f * LOG2PI_F + la;
            }
            // softmax over o: 5-level xor-reduce within each 32-lane half
#pragma unroll
            for (int cl = 0; cl < 16; ++cl) {
                float m = lg[cl];
                m = fmaxf(m, __shfl_xor(m, 1));
                m = fmaxf(m, __shfl_xor(m, 2));
                m = fmaxf(m, __shfl_xor(m, 4));
                m = fmaxf(m, __shfl_xor(m, 8));
                m = fmaxf(m, __shfl_xor(m, 16));
                float e = __expf(lg[cl] - m);
                float ssum = e;
                ssum += __shfl_xor(ssum, 1);
                ssum += __shfl_xor(ssum, 2);
                ssum += __shfl_xor(ssum, 4);
                ssum += __shfl_xor(ssum, 8);
                ssum += __shfl_xor(ssum, 16);
                r[cl] = e / ssum;
            }
        }
    }

    // outputs (both halves hold identical mu/aout; h==0 writes)
    if (h == 0) {
        float4 val = {mu[0], mu[1], mu[2], mu[3]};
        float4* po = (float4*)(out + n * 512 + o * 16);
        po[0] = val; po[1] = val; po[2] = val; po[3] = val;
        out[1179648 + n * 32 + o] = aout;
    }
}

extern "C" void kernel_launch(void* const* d_in, const int* in_sizes, int n_in,
                              void* d_out, int out_size, void* d_ws, size_t ws_size,
                              hipStream_t stream) {
    const float* x = (const float*)d_in[0];
    const float* a = (const float*)d_in[1];
    const float* w = (const float*)d_in[2];
    const float* bu = (const float*)d_in[3];
    const float* ba = (const float*)d_in[4];
    float* out = (float*)d_out;

    float* S    = (float*)d_ws;          // 36864
    float* A    = S + 36864;             // 2304
    float* Wsum = A + 2304;              // 147456

    pre_kernel<<<272 + 576, 256, 0, stream>>>(x, a, w, S, A, Wsum);
    em_kernel<<<576, 256, 0, stream>>>(bu, ba, S, A, Wsum, out);
}

// Round 4
// 27.375 us; speedup vs baseline: 5.5982x; 1.2868x over previous
//
#include <hip/hip_runtime.h>
#include <math.h>

// ConvCaps EM-routing, MI355X — wave-per-group, register-resident EM,
// tree reductions + packed-f32 + transposed-LDS softmax.
//
// Algebra: vv[n,ci,co,k] = Sv(n,ci,co>>1) * Wsum(sp=n%36,ci,co,k&3), so EM
// runs on a 32x32x4 table. One 64-lane wave per group: lane=(h,o), h=c-half.

#define EPSF 1e-8f

typedef float f2 __attribute__((ext_vector_type(2)));

// ---- pre: box-filtered channel sums (S,A) + Wsum[36][32][32][4] ----
__global__ __launch_bounds__(256) void pre_kernel(
        const float* __restrict__ x, const float* __restrict__ a,
        const float* __restrict__ w,
        float* __restrict__ S, float* __restrict__ A, float* __restrict__ Wsum) {
    int bid = blockIdx.x;
    if (bid < 544) {
        // 2 planes per block, 2 waves per plane (16-channel halves).
        __shared__ float part[2][2][200];
        int wv = threadIdx.x >> 6, lane = threadIdx.x & 63;
        int pl = wv >> 1, ch = wv & 1;
        int p = bid * 2 + pl;                     // 0..1087 (1024 x + 64 a planes)
        const float* src = (p < 1024) ? (x + (size_t)p * 6272)
                                      : (a + (size_t)(p - 1024) * 6272);
        src += ch * (16 * 196);
        if (lane < 49) {
            float4 s = {0.f, 0.f, 0.f, 0.f};
#pragma unroll
            for (int c = 0; c < 16; ++c) {
                float4 v = *(const float4*)(src + c * 196 + lane * 4);
                s.x += v.x; s.y += v.y; s.z += v.z; s.w += v.w;
            }
            *(float4*)(&part[pl][ch][lane * 4]) = s;
        }
        __syncthreads();
        if ((wv & 1) == 0 && lane < 36) {
            int pl2 = wv >> 1;
            int oy = lane / 6, ox = lane - oy * 6;
            const float* q0 = &part[pl2][0][oy * 28 + ox * 2];
            const float* q1 = &part[pl2][1][oy * 28 + ox * 2];
            float s = 0.f;
#pragma unroll
            for (int ky = 0; ky < 3; ++ky)
                s += q0[ky * 14] + q0[ky * 14 + 1] + q0[ky * 14 + 2]
                   + q1[ky * 14] + q1[ky * 14 + 1] + q1[ky * 14 + 2];
            s *= (1.0f / 9.0f);
            int pp = bid * 2 + pl2;
            if (pp < 1024) S[pp * 36 + lane] = s;
            else           A[(pp - 1024) * 36 + lane] = s;
        }
    } else {
        int wi = (bid - 544) * 256 + threadIdx.x;   // 147456 Wsum entries
        int sp = wi >> 12;
        int rr = wi & 4095;
        int ci = rr >> 7, co = (rr >> 2) & 31, j = rr & 3;
        int B = sp * 32 + ci;
        int cc = B / 36;
        int rem = B - cc * 36;
        int wbase = cc * 18432 + (rem / 6) * 3072 + (rem % 6) * 512 + co * 16 + j;
        Wsum[wi] = w[wbase] + w[wbase + 4] + w[wbase + 8] + w[wbase + 12];
    }
}

// ---- EM: one wave per routing group, 4 groups per block, no barriers ----
__global__ __launch_bounds__(256) void em_kernel(
        const float* __restrict__ bu, const float* __restrict__ ba,
        const float* __restrict__ S, const float* __restrict__ A,
        const float* __restrict__ Wsum, float* __restrict__ out) {
    __shared__ float Sv[4][512];
    __shared__ float avs[4][32];
    __shared__ float lgb[4][33 * 32];   // [c][o] rows, stride 33

    const int t = threadIdx.x;
    const int g = t >> 6;
    const int lane = t & 63;
    const int h = lane >> 5;
    const int o = lane & 31;
    const int n = blockIdx.x * 4 + g;
    const int bq = n / 36;
    const int sp = n - bq * 36;

    if (lane < 32) avs[g][lane] = A[bq * 36 + (32 * sp + lane) % 36];
    for (int e = lane; e < 512; e += 64) {
        int ci = e >> 4, hc2 = e & 15;
        int B = sp * 32 + ci;
        int cc = B / 36;
        int rem = B - cc * 36;
        int off = cc * 576 + (rem / 6) * 96 + (rem % 6) * 16 + hc2;
        int hi = off / 1152;
        int lo = off - hi * 1152;
        Sv[g][e] = S[(bq * 16 + hi) * 36 + lo % 36];
    }
    // (all LDS traffic below is wave-local: no __syncthreads needed)

    const int hc = o >> 1;
    f2 V2[16][2];
    float avr[16], r[16];
    const float* Wn = Wsum + sp * 4096;
#pragma unroll
    for (int cl = 0; cl < 16; ++cl) {
        int c = h * 16 + cl;
        float sv = Sv[g][c * 16 + hc];
        float4 w4 = *(const float4*)(Wn + c * 128 + o * 4);
        V2[cl][0] = (f2){sv * w4.x, sv * w4.y};
        V2[cl][1] = (f2){sv * w4.z, sv * w4.w};
        avr[cl] = avs[g][c];
        r[cl] = 0.03125f;
    }
    const float bu_o = bu[o];
    const float ba_o = ba[o];
    f2 mu2[2], q2[2];
    float aout = 0.f;
    const float lambdas[3] = {5.0e-4f, 9.75e-4f, 1.42625e-3f};

    for (int it = 0; it < 3; ++it) {
        float rp[16];
#pragma unroll
        for (int cl = 0; cl < 16; ++cl) rp[cl] = r[cl] * avr[cl] + EPSF;
        // tree rsum
        float rs;
        {
            float t0 = rp[0]+rp[1], t1 = rp[2]+rp[3], t2 = rp[4]+rp[5], t3 = rp[6]+rp[7];
            float t4 = rp[8]+rp[9], t5 = rp[10]+rp[11], t6 = rp[12]+rp[13], t7 = rp[14]+rp[15];
            rs = ((t0+t1)+(t2+t3)) + ((t4+t5)+(t6+t7));
        }
        rs += __shfl_xor(rs, 32);
        float rinv = 1.0f / rs;
        // mu (packed, 4-way tree)
#pragma unroll
        for (int p = 0; p < 2; ++p) {
            f2 a0 = {0.f,0.f}, a1 = {0.f,0.f}, a2 = {0.f,0.f}, a3 = {0.f,0.f};
#pragma unroll
            for (int cl = 0; cl < 16; cl += 4) {
                a0 += rp[cl]     * V2[cl][p];
                a1 += rp[cl + 1] * V2[cl + 1][p];
                a2 += rp[cl + 2] * V2[cl + 2][p];
                a3 += rp[cl + 3] * V2[cl + 3][p];
            }
            f2 m = (a0 + a1) + (a2 + a3);
            m.x += __shfl_xor(m.x, 32);
            m.y += __shfl_xor(m.y, 32);
            mu2[p] = m * rinv;
        }
        // sig (packed, 4-way tree) -> ls (0.5 log), q (2/sig)
        float ls_sum;
        {
            float lsp[4];
#pragma unroll
            for (int p = 0; p < 2; ++p) {
                f2 a0 = {0.f,0.f}, a1 = {0.f,0.f}, a2 = {0.f,0.f}, a3 = {0.f,0.f};
#pragma unroll
                for (int cl = 0; cl < 16; cl += 4) {
                    f2 d0 = V2[cl][p]     - mu2[p];
                    f2 d1 = V2[cl + 1][p] - mu2[p];
                    f2 d2 = V2[cl + 2][p] - mu2[p];
                    f2 d3 = V2[cl + 3][p] - mu2[p];
                    a0 += (d0 * d0) * rp[cl];
                    a1 += (d1 * d1) * rp[cl + 1];
                    a2 += (d2 * d2) * rp[cl + 2];
                    a3 += (d3 * d3) * rp[cl + 3];
                }
                f2 sg = ((a0 + a1) + (a2 + a3));
                sg.x += __shfl_xor(sg.x, 32);
                sg.y += __shfl_xor(sg.y, 32);
                sg = sg * rinv + EPSF;
                lsp[2 * p]     = 0.5f * __logf(sg.x);
                lsp[2 * p + 1] = 0.5f * __logf(sg.y);
                q2[p] = (f2){2.0f / sg.x, 2.0f / sg.y};
            }
            ls_sum = (lsp[0] + lsp[1]) + (lsp[2] + lsp[3]);
        }
        float cost = (16.0f * bu_o + 4.0f * ls_sum) * rs;
        float z = lambdas[it] * (ba_o - cost);
        aout = 1.0f / (1.0f + __expf(-z));

        if (it < 2) {
            // logits (softmax-invariant constant -8*log2pi dropped)
            float T = __logf(aout) - 4.0f * ls_sum;
#pragma unroll
            for (int cl = 0; cl < 16; ++cl) {
                f2 d0 = V2[cl][0] - mu2[0];
                f2 d1 = V2[cl][1] - mu2[1];
                f2 s2 = (d0 * d0) * q2[0] + (d1 * d1) * q2[1];
                lgb[g][(h * 16 + cl) * 33 + o] = T - (s2.x + s2.y);
            }
            // transposed softmax: lane = (oh, c-row); register-local over 16 o
            {
                int cT = lane & 31, oh = lane >> 5;
                float* rowp = &lgb[g][cT * 33 + oh * 16];
                float4 u0 = *(float4*)(rowp);
                float4 u1 = *(float4*)(rowp + 4);
                float4 u2 = *(float4*)(rowp + 8);
                float4 u3 = *(float4*)(rowp + 12);
                float m0 = fmaxf(fmaxf(u0.x, u0.y), fmaxf(u0.z, u0.w));
                float m1 = fmaxf(fmaxf(u1.x, u1.y), fmaxf(u1.z, u1.w));
                float m2 = fmaxf(fmaxf(u2.x, u2.y), fmaxf(u2.z, u2.w));
                float m3 = fmaxf(fmaxf(u3.x, u3.y), fmaxf(u3.z, u3.w));
                float m = fmaxf(fmaxf(m0, m1), fmaxf(m2, m3));
                m = fmaxf(m, __shfl_xor(m, 32));
                u0.x = __expf(u0.x - m); u0.y = __expf(u0.y - m);
                u0.z = __expf(u0.z - m); u0.w = __expf(u0.w - m);
                u1.x = __expf(u1.x - m); u1.y = __expf(u1.y - m);
                u1.z = __expf(u1.z - m); u1.w = __expf(u1.w - m);
                u2.x = __expf(u2.x - m); u2.y = __expf(u2.y - m);
                u2.z = __expf(u2.z - m); u2.w = __expf(u2.w - m);
                u3.x = __expf(u3.x - m); u3.y = __expf(u3.y - m);
                u3.z = __expf(u3.z - m); u3.w = __expf(u3.w - m);
                float s0 = (u0.x + u0.y) + (u0.z + u0.w);
                float s1 = (u1.x + u1.y) + (u1.z + u1.w);
                float s2 = (u2.x + u2.y) + (u2.z + u2.w);
                float s3 = (u3.x + u3.y) + (u3.z + u3.w);
                float ssum = (s0 + s1) + (s2 + s3);
                ssum += __shfl_xor(ssum, 32);
                float inv = 1.0f / ssum;
                u0.x *= inv; u0.y *= inv; u0.z *= inv; u0.w *= inv;
                u1.x *= inv; u1.y *= inv; u1.z *= inv; u1.w *= inv;
                u2.x *= inv; u2.y *= inv; u2.z *= inv; u2.w *= inv;
                u3.x *= inv; u3.y *= inv; u3.z *= inv; u3.w *= inv;
                *(float4*)(rowp)      = u0;
                *(float4*)(rowp + 4)  = u1;
                *(float4*)(rowp + 8)  = u2;
                *(float4*)(rowp + 12) = u3;
            }
#pragma unroll
            for (int cl = 0; cl < 16; ++cl)
                r[cl] = lgb[g][(h * 16 + cl) * 33 + o];
        }
    }

    // outputs: mu expanded to 16 k (k>>2 drops out); both halves hold identical mu
    float4 val = {mu2[0].x, mu2[0].y, mu2[1].x, mu2[1].y};
    float4* po = (float4*)(out + n * 512 + o * 16);
    po[2 * h] = val;
    po[2 * h + 1] = val;
    if (h == 0) out[1179648 + n * 32 + o] = aout;
}

extern "C" void kernel_launch(void* const* d_in, const int* in_sizes, int n_in,
                              void* d_out, int out_size, void* d_ws, size_t ws_size,
                              hipStream_t stream) {
    const float* x = (const float*)d_in[0];
    const float* a = (const float*)d_in[1];
    const float* w = (const float*)d_in[2];
    const float* bu = (const float*)d_in[3];
    const float* ba = (const float*)d_in[4];
    float* out = (float*)d_out;

    float* S    = (float*)d_ws;          // 36864
    float* A    = S + 36864;             // 2304
    float* Wsum = A + 2304;              // 147456

    pre_kernel<<<544 + 576, 256, 0, stream>>>(x, a, w, S, A, Wsum);
    em_kernel<<<576, 256, 0, stream>>>(bu, ba, S, A, Wsum, out);
}

// Round 6
// 26.561 us; speedup vs baseline: 5.7698x; 1.0306x over previous
//
#include <hip/hip_runtime.h>
#include <math.h>

// ConvCaps EM-routing, MI355X — 2-wave-per-group with o-split ownership.
//
// Algebra: vv[n,ci,co,k] = Sv(n,ci,co>>1) * Wsum(sp=n%36,ci,co,k&3), so EM
// runs on a 32x32x4 table. Block = 128 threads (2 waves) per group.
// Wave w owns o = w*16 + (lane&15); cq = lane>>4 owns c = cq*8..cq*8+7.
// M-step reductions over c: in-register tree + shfl_xor(16)+shfl_xor(32)
// (wave-local, two-pass mu->sig: no E[V^2] cancellation, no barriers).
// E-step softmax over o crosses waves via the transposed LDS logit table.

#define EPSF 1e-8f

typedef float f2 __attribute__((ext_vector_type(2)));

// ---- pre: box-filtered channel sums (S,A) + Wsum[36][32][32][4] ----
__global__ __launch_bounds__(256) void pre_kernel(
        const float* __restrict__ x, const float* __restrict__ a,
        const float* __restrict__ w,
        float* __restrict__ S, float* __restrict__ A, float* __restrict__ Wsum) {
    int bid = blockIdx.x;
    if (bid < 544) {
        // 2 planes per block, 2 waves per plane (16-channel halves).
        __shared__ float part[2][2][200];
        int wv = threadIdx.x >> 6, lane = threadIdx.x & 63;
        int pl = wv >> 1, ch = wv & 1;
        int p = bid * 2 + pl;                     // 0..1087 (1024 x + 64 a planes)
        const float* src = (p < 1024) ? (x + (size_t)p * 6272)
                                      : (a + (size_t)(p - 1024) * 6272);
        src += ch * (16 * 196);
        if (lane < 49) {
            float4 s = {0.f, 0.f, 0.f, 0.f};
#pragma unroll
            for (int c = 0; c < 16; ++c) {
                float4 v = *(const float4*)(src + c * 196 + lane * 4);
                s.x += v.x; s.y += v.y; s.z += v.z; s.w += v.w;
            }
            *(float4*)(&part[pl][ch][lane * 4]) = s;
        }
        __syncthreads();
        if ((wv & 1) == 0 && lane < 36) {
            int pl2 = wv >> 1;
            int oy = lane / 6, ox = lane - oy * 6;
            const float* q0 = &part[pl2][0][oy * 28 + ox * 2];
            const float* q1 = &part[pl2][1][oy * 28 + ox * 2];
            float s = 0.f;
#pragma unroll
            for (int ky = 0; ky < 3; ++ky)
                s += q0[ky * 14] + q0[ky * 14 + 1] + q0[ky * 14 + 2]
                   + q1[ky * 14] + q1[ky * 14 + 1] + q1[ky * 14 + 2];
            s *= (1.0f / 9.0f);
            int pp = bid * 2 + pl2;
            if (pp < 1024) S[pp * 36 + lane] = s;
            else           A[(pp - 1024) * 36 + lane] = s;
        }
    } else {
        int wi = (bid - 544) * 256 + threadIdx.x;   // 147456 Wsum entries
        int sp = wi >> 12;
        int rr = wi & 4095;
        int ci = rr >> 7, co = (rr >> 2) & 31, j = rr & 3;
        int B = sp * 32 + ci;
        int cc = B / 36;
        int rem = B - cc * 36;
        int wbase = cc * 18432 + (rem / 6) * 3072 + (rem % 6) * 512 + co * 16 + j;
        Wsum[wi] = w[wbase] + w[wbase + 4] + w[wbase + 8] + w[wbase + 12];
    }
}

// ---- EM: one 128-thread block (2 waves) per routing group ----
__global__ __launch_bounds__(128, 4) void em_kernel(
        const float* __restrict__ bu, const float* __restrict__ ba,
        const float* __restrict__ S, const float* __restrict__ A,
        const float* __restrict__ Wsum, float* __restrict__ out) {
    __shared__ float Sv[512];
    __shared__ float avs[32];
    __shared__ float lgb[33 * 32];      // [c][o], stride 33

    const int t = threadIdx.x;
    const int w = t >> 6;
    const int lane = t & 63;
    const int o = w * 16 + (lane & 15); // owned output capsule
    const int cq = lane >> 4;           // c-quarter (0..3)
    const int c0 = cq * 8;
    const int n = blockIdx.x;
    const int bq = n / 36;
    const int sp = n - bq * 36;

    if (t < 32) avs[t] = A[bq * 36 + (32 * sp + t) % 36];
    for (int e = t; e < 512; e += 128) {
        int ci = e >> 4, hc2 = e & 15;
        int B = sp * 32 + ci;
        int cc = B / 36;
        int rem = B - cc * 36;
        int off = cc * 576 + (rem / 6) * 96 + (rem % 6) * 16 + hc2;
        int hi = off / 1152;
        int lo = off - hi * 1152;
        Sv[e] = S[(bq * 16 + hi) * 36 + lo % 36];
    }
    __syncthreads();

    const int hc = o >> 1;
    f2 V2[8][2];
    float avr[8], r[8];
    const float* Wn = Wsum + sp * 4096;
#pragma unroll
    for (int cl = 0; cl < 8; ++cl) {
        int c = c0 + cl;
        float sv = Sv[c * 16 + hc];
        float4 w4 = *(const float4*)(Wn + c * 128 + o * 4);
        V2[cl][0] = (f2){sv * w4.x, sv * w4.y};
        V2[cl][1] = (f2){sv * w4.z, sv * w4.w};
        avr[cl] = avs[c];
        r[cl] = 0.03125f;
    }
    const float bu_o = bu[o];
    const float ba_o = ba[o];
    f2 mu2[2], q2[2];
    float aout = 0.f;
    const float lambdas[3] = {5.0e-4f, 9.75e-4f, 1.42625e-3f};

    for (int it = 0; it < 3; ++it) {
        // ---- pass 1: rp, rs, S1[j] = sum rp*V (wave-local reduce over c) ----
        float rp[8];
#pragma unroll
        for (int cl = 0; cl < 8; ++cl) rp[cl] = r[cl] * avr[cl] + EPSF;
        float rs = ((rp[0] + rp[1]) + (rp[2] + rp[3]))
                 + ((rp[4] + rp[5]) + (rp[6] + rp[7]));
        rs += __shfl_xor(rs, 16);
        rs += __shfl_xor(rs, 32);
        float rinv = 1.0f / rs;
#pragma unroll
        for (int p = 0; p < 2; ++p) {
            f2 a0 = {0.f, 0.f}, a1 = {0.f, 0.f};
#pragma unroll
            for (int cl = 0; cl < 8; cl += 2) {
                a0 += rp[cl] * V2[cl][p];
                a1 += rp[cl + 1] * V2[cl + 1][p];
            }
            f2 m = a0 + a1;
            m.x += __shfl_xor(m.x, 16); m.x += __shfl_xor(m.x, 32);
            m.y += __shfl_xor(m.y, 16); m.y += __shfl_xor(m.y, 32);
            mu2[p] = m * rinv;
        }
        // ---- pass 2: sig (non-negative by construction) ----
        float ls_sum;
        {
            float lsp[4];
#pragma unroll
            for (int p = 0; p < 2; ++p) {
                f2 a0 = {0.f, 0.f}, a1 = {0.f, 0.f};
#pragma unroll
                for (int cl = 0; cl < 8; cl += 2) {
                    f2 d0 = V2[cl][p] - mu2[p];
                    f2 d1 = V2[cl + 1][p] - mu2[p];
                    a0 += (d0 * d0) * rp[cl];
                    a1 += (d1 * d1) * rp[cl + 1];
                }
                f2 sg = a0 + a1;
                sg.x += __shfl_xor(sg.x, 16); sg.x += __shfl_xor(sg.x, 32);
                sg.y += __shfl_xor(sg.y, 16); sg.y += __shfl_xor(sg.y, 32);
                sg = sg * rinv + EPSF;
                lsp[2 * p]     = 0.5f * __logf(sg.x);
                lsp[2 * p + 1] = 0.5f * __logf(sg.y);
                q2[p] = (f2){2.0f / sg.x, 2.0f / sg.y};
            }
            ls_sum = (lsp[0] + lsp[1]) + (lsp[2] + lsp[3]);
        }
        float cost = (16.0f * bu_o + 4.0f * ls_sum) * rs;
        float z = lambdas[it] * (ba_o - cost);
        aout = 1.0f / (1.0f + __expf(-z));

        if (it < 2) {
            // logits (softmax-invariant -8*log2pi dropped)
            float T = __logf(aout) - 4.0f * ls_sum;
#pragma unroll
            for (int cl = 0; cl < 8; ++cl) {
                f2 d0 = V2[cl][0] - mu2[0];
                f2 d1 = V2[cl][1] - mu2[1];
                f2 s2 = (d0 * d0) * q2[0] + (d1 * d1) * q2[1];
                lgb[(c0 + cl) * 33 + o] = T - (s2.x + s2.y);
            }
            __syncthreads();
            // transposed softmax: 128 lanes, lane = (c-row, quarter of o-row)
            {
                int cT = t >> 2, q = t & 3;
                float* rowp = &lgb[cT * 33 + q * 8];
                float4 u0 = *(float4*)(rowp);
                float4 u1 = *(float4*)(rowp + 4);
                float m0 = fmaxf(fmaxf(u0.x, u0.y), fmaxf(u0.z, u0.w));
                float m1 = fmaxf(fmaxf(u1.x, u1.y), fmaxf(u1.z, u1.w));
                float m = fmaxf(m0, m1);
                m = fmaxf(m, __shfl_xor(m, 1));
                m = fmaxf(m, __shfl_xor(m, 2));
                u0.x = __expf(u0.x - m); u0.y = __expf(u0.y - m);
                u0.z = __expf(u0.z - m); u0.w = __expf(u0.w - m);
                u1.x = __expf(u1.x - m); u1.y = __expf(u1.y - m);
                u1.z = __expf(u1.z - m); u1.w = __expf(u1.w - m);
                float s0 = (u0.x + u0.y) + (u0.z + u0.w);
                float s1 = (u1.x + u1.y) + (u1.z + u1.w);
                float ssum = s0 + s1;
                ssum += __shfl_xor(ssum, 1);
                ssum += __shfl_xor(ssum, 2);
                float inv = 1.0f / ssum;
                u0.x *= inv; u0.y *= inv; u0.z *= inv; u0.w *= inv;
                u1.x *= inv; u1.y *= inv; u1.z *= inv; u1.w *= inv;
                *(float4*)(rowp)     = u0;
                *(float4*)(rowp + 4) = u1;
            }
            __syncthreads();
#pragma unroll
            for (int cl = 0; cl < 8; ++cl)
                r[cl] = lgb[(c0 + cl) * 33 + o];
        }
    }

    // outputs: mu expanded to 16 k (k>>2 drops out); 4 cq-lanes hold identical
    // mu for their o — each writes one float4 quarter of the 16-k row.
    float4 val = {mu2[0].x, mu2[0].y, mu2[1].x, mu2[1].y};
    float4* po = (float4*)(out + n * 512 + o * 16);
    po[cq] = val;
    if (cq == 0) out[1179648 + n * 32 + o] = aout;
}

extern "C" void kernel_launch(void* const* d_in, const int* in_sizes, int n_in,
                              void* d_out, int out_size, void* d_ws, size_t ws_size,
                              hipStream_t stream) {
    const float* x = (const float*)d_in[0];
    const float* a = (const float*)d_in[1];
    const float* w = (const float*)d_in[2];
    const float* bu = (const float*)d_in[3];
    const float* ba = (const float*)d_in[4];
    float* out = (float*)d_out;

    float* S    = (float*)d_ws;          // 36864
    float* A    = S + 36864;             // 2304
    float* Wsum = A + 2304;              // 147456

    pre_kernel<<<544 + 576, 256, 0, stream>>>(x, a, w, S, A, Wsum);
    em_kernel<<<2304, 128, 0, stream>>>(bu, ba, S, A, Wsum, out);
}

// Round 7
// 26.074 us; speedup vs baseline: 5.8775x; 1.0187x over previous
//
#include <hip/hip_runtime.h>
#include <math.h>

// ConvCaps EM-routing, MI355X — coalesced plane-staged pre + 2-wave o-split EM.
//
// Algebra: vv[n,ci,co,k] = Sv(n,ci,co>>1) * Wsum(sp=n%36,ci,co,k&3), so EM
// runs on a 32x32x4 table. EM block = 128 threads (2 waves) per group.
// Wave w owns o = w*16 + (lane&15); cq = lane>>4 owns c = cq*8..cq*8+7.

#define EPSF 1e-8f

typedef float f2 __attribute__((ext_vector_type(2)));

// ---- pre: box-filtered channel sums (S,A) + Wsum[36][32][32][4] ----
// bid < 1088: one plane per block. Stage raw plane to LDS (fully coalesced
// float4), channel-sum with conflict-free LDS reads, 3x3/2 box filter.
__global__ __launch_bounds__(256) void pre_kernel(
        const float* __restrict__ x, const float* __restrict__ a,
        const float* __restrict__ w,
        float* __restrict__ S, float* __restrict__ A, float* __restrict__ Wsum) {
    int bid = blockIdx.x;
    if (bid < 1088) {
        __shared__ float plane[6272];
        __shared__ float bsum[196];
        const int t = threadIdx.x;
        const float* src = (bid < 1024) ? (x + (size_t)bid * 6272)
                                        : (a + (size_t)(bid - 1024) * 6272);
        // 1568 float4 = whole plane, 256 lanes x 16B per instr
        for (int k = t; k < 1568; k += 256)
            *(float4*)&plane[k * 4] = *(const float4*)(src + k * 4);
        __syncthreads();
        if (t < 196) {
            float s = 0.f;
#pragma unroll
            for (int c = 0; c < 32; ++c) s += plane[c * 196 + t];
            bsum[t] = s;
        }
        __syncthreads();
        if (t < 36) {
            int oy = t / 6, ox = t - oy * 6;
            const float* q = &bsum[oy * 28 + ox * 2];
            float s = (q[0] + q[1] + q[2]) + (q[14] + q[15] + q[16])
                    + (q[28] + q[29] + q[30]);
            s *= (1.0f / 9.0f);
            if (bid < 1024) S[bid * 36 + t] = s;
            else            A[(bid - 1024) * 36 + t] = s;
        }
    } else {
        int wi = (bid - 1088) * 256 + threadIdx.x;   // 147456 Wsum entries
        int sp = wi >> 12;
        int rr = wi & 4095;
        int ci = rr >> 7, co = (rr >> 2) & 31, j = rr & 3;
        int B = sp * 32 + ci;
        int cc = B / 36;
        int rem = B - cc * 36;
        int wbase = cc * 18432 + (rem / 6) * 3072 + (rem % 6) * 512 + co * 16 + j;
        Wsum[wi] = w[wbase] + w[wbase + 4] + w[wbase + 8] + w[wbase + 12];
    }
}

// ---- EM: one 128-thread block (2 waves) per routing group ----
__global__ __launch_bounds__(128, 4) void em_kernel(
        const float* __restrict__ bu, const float* __restrict__ ba,
        const float* __restrict__ S, const float* __restrict__ A,
        const float* __restrict__ Wsum, float* __restrict__ out) {
    __shared__ float Sv[512];
    __shared__ float avs[32];
    __shared__ float lgb[33 * 32];      // [c][o], stride 33

    const int t = threadIdx.x;
    const int w = t >> 6;
    const int lane = t & 63;
    const int o = w * 16 + (lane & 15); // owned output capsule
    const int cq = lane >> 4;           // c-quarter (0..3)
    const int c0 = cq * 8;
    const int n = blockIdx.x;
    const int bq = n / 36;
    const int sp = n - bq * 36;

    if (t < 32) avs[t] = A[bq * 36 + (32 * sp + t) % 36];
    for (int e = t; e < 512; e += 128) {
        int ci = e >> 4, hc2 = e & 15;
        int B = sp * 32 + ci;
        int cc = B / 36;
        int rem = B - cc * 36;
        int off = cc * 576 + (rem / 6) * 96 + (rem % 6) * 16 + hc2;
        int hi = off / 1152;
        int lo = off - hi * 1152;
        Sv[e] = S[(bq * 16 + hi) * 36 + lo % 36];
    }
    __syncthreads();

    const int hc = o >> 1;
    f2 V2[8][2];
    float avr[8], r[8];
    const float* Wn = Wsum + sp * 4096;
#pragma unroll
    for (int cl = 0; cl < 8; ++cl) {
        int c = c0 + cl;
        float sv = Sv[c * 16 + hc];
        float4 w4 = *(const float4*)(Wn + c * 128 + o * 4);
        V2[cl][0] = (f2){sv * w4.x, sv * w4.y};
        V2[cl][1] = (f2){sv * w4.z, sv * w4.w};
        avr[cl] = avs[c];
        r[cl] = 0.03125f;
    }
    const float bu_o = bu[o];
    const float ba_o = ba[o];
    f2 mu2[2], q2[2];
    float aout = 0.f;
    const float lambdas[3] = {5.0e-4f, 9.75e-4f, 1.42625e-3f};

    for (int it = 0; it < 3; ++it) {
        // ---- pass 1: rp, rs, S1[j] = sum rp*V (wave-local reduce over c) ----
        float rp[8];
#pragma unroll
        for (int cl = 0; cl < 8; ++cl) rp[cl] = r[cl] * avr[cl] + EPSF;
        float rs = ((rp[0] + rp[1]) + (rp[2] + rp[3]))
                 + ((rp[4] + rp[5]) + (rp[6] + rp[7]));
        rs += __shfl_xor(rs, 16);
        rs += __shfl_xor(rs, 32);
        float rinv = 1.0f / rs;
#pragma unroll
        for (int p = 0; p < 2; ++p) {
            f2 a0 = {0.f, 0.f}, a1 = {0.f, 0.f};
#pragma unroll
            for (int cl = 0; cl < 8; cl += 2) {
                a0 += rp[cl] * V2[cl][p];
                a1 += rp[cl + 1] * V2[cl + 1][p];
            }
            f2 m = a0 + a1;
            m.x += __shfl_xor(m.x, 16); m.x += __shfl_xor(m.x, 32);
            m.y += __shfl_xor(m.y, 16); m.y += __shfl_xor(m.y, 32);
            mu2[p] = m * rinv;
        }
        // ---- pass 2: sig (non-negative by construction) ----
        float ls_sum;
        {
            float lsp[4];
#pragma unroll
            for (int p = 0; p < 2; ++p) {
                f2 a0 = {0.f, 0.f}, a1 = {0.f, 0.f};
#pragma unroll
                for (int cl = 0; cl < 8; cl += 2) {
                    f2 d0 = V2[cl][p] - mu2[p];
                    f2 d1 = V2[cl + 1][p] - mu2[p];
                    a0 += (d0 * d0) * rp[cl];
                    a1 += (d1 * d1) * rp[cl + 1];
                }
                f2 sg = a0 + a1;
                sg.x += __shfl_xor(sg.x, 16); sg.x += __shfl_xor(sg.x, 32);
                sg.y += __shfl_xor(sg.y, 16); sg.y += __shfl_xor(sg.y, 32);
                sg = sg * rinv + EPSF;
                lsp[2 * p]     = 0.5f * __logf(sg.x);
                lsp[2 * p + 1] = 0.5f * __logf(sg.y);
                q2[p] = (f2){2.0f / sg.x, 2.0f / sg.y};
            }
            ls_sum = (lsp[0] + lsp[1]) + (lsp[2] + lsp[3]);
        }
        float cost = (16.0f * bu_o + 4.0f * ls_sum) * rs;
        float z = lambdas[it] * (ba_o - cost);
        aout = 1.0f / (1.0f + __expf(-z));

        if (it < 2) {
            // logits (softmax-invariant -8*log2pi dropped)
            float T = __logf(aout) - 4.0f * ls_sum;
#pragma unroll
            for (int cl = 0; cl < 8; ++cl) {
                f2 d0 = V2[cl][0] - mu2[0];
                f2 d1 = V2[cl][1] - mu2[1];
                f2 s2 = (d0 * d0) * q2[0] + (d1 * d1) * q2[1];
                lgb[(c0 + cl) * 33 + o] = T - (s2.x + s2.y);
            }
            __syncthreads();
            // transposed softmax: 128 lanes, lane = (c-row, quarter of o-row)
            {
                int cT = t >> 2, q = t & 3;
                float* rowp = &lgb[cT * 33 + q * 8];
                float4 u0 = *(float4*)(rowp);
                float4 u1 = *(float4*)(rowp + 4);
                float m0 = fmaxf(fmaxf(u0.x, u0.y), fmaxf(u0.z, u0.w));
                float m1 = fmaxf(fmaxf(u1.x, u1.y), fmaxf(u1.z, u1.w));
                float m = fmaxf(m0, m1);
                m = fmaxf(m, __shfl_xor(m, 1));
                m = fmaxf(m, __shfl_xor(m, 2));
                u0.x = __expf(u0.x - m); u0.y = __expf(u0.y - m);
                u0.z = __expf(u0.z - m); u0.w = __expf(u0.w - m);
                u1.x = __expf(u1.x - m); u1.y = __expf(u1.y - m);
                u1.z = __expf(u1.z - m); u1.w = __expf(u1.w - m);
                float s0 = (u0.x + u0.y) + (u0.z + u0.w);
                float s1 = (u1.x + u1.y) + (u1.z + u1.w);
                float ssum = s0 + s1;
                ssum += __shfl_xor(ssum, 1);
                ssum += __shfl_xor(ssum, 2);
                float inv = 1.0f / ssum;
                u0.x *= inv; u0.y *= inv; u0.z *= inv; u0.w *= inv;
                u1.x *= inv; u1.y *= inv; u1.z *= inv; u1.w *= inv;
                *(float4*)(rowp)     = u0;
                *(float4*)(rowp + 4) = u1;
            }
            __syncthreads();
#pragma unroll
            for (int cl = 0; cl < 8; ++cl)
                r[cl] = lgb[(c0 + cl) * 33 + o];
        }
    }

    // outputs: mu expanded to 16 k (k>>2 drops out); 4 cq-lanes hold identical
    // mu for their o — each writes one float4 quarter of the 16-k row.
    float4 val = {mu2[0].x, mu2[0].y, mu2[1].x, mu2[1].y};
    float4* po = (float4*)(out + n * 512 + o * 16);
    po[cq] = val;
    if (cq == 0) out[1179648 + n * 32 + o] = aout;
}

extern "C" void kernel_launch(void* const* d_in, const int* in_sizes, int n_in,
                              void* d_out, int out_size, void* d_ws, size_t ws_size,
                              hipStream_t stream) {
    const float* x = (const float*)d_in[0];
    const float* a = (const float*)d_in[1];
    const float* w = (const float*)d_in[2];
    const float* bu = (const float*)d_in[3];
    const float* ba = (const float*)d_in[4];
    float* out = (float*)d_out;

    float* S    = (float*)d_ws;          // 36864
    float* A    = S + 36864;             // 2304
    float* Wsum = A + 2304;              // 147456

    pre_kernel<<<1088 + 576, 256, 0, stream>>>(x, a, w, S, A, Wsum);
    em_kernel<<<2304, 128, 0, stream>>>(bu, ba, S, A, Wsum, out);
}